// Round 8
// baseline (164.794 us; speedup 1.0000x reference)
//
#include <hip/hip_runtime.h>
#include <hip/hip_cooperative_groups.h>

namespace cg = cooperative_groups;

#define H 1024
#define W 1024
#define L 8
#define QH 1025
#define QW 1025
#define OUT0 192
#define QUANT_ELEMS (L * QH * QW)

#define UROWS 16              // rows per unit
#define NUNITS 512            // 32 chunks x 8 i-groups x 2 halves = 2 blocks/CU
// unit u: c = u>>4 (chunk of 32 rows), i = (u>>1)&7, half = u&1

// ws float slots (every slot written unconditionally every call -> no init,
// no atomics, deterministic under graph replay):
// [0..511] min partials, [512..1023] max partials,
// [1024..5119] sta partials: slot (c*2+half)*64 + (i*8+j), exclusive per block
#define WS_MINP 0
#define WS_MAXP 512
#define WS_STA  1024

__device__ __forceinline__ float qlev(float mn, float step, float mx, int i) {
    return (i == L - 1) ? mx : mn + step * (float)i;
}
__device__ __forceinline__ float ex16(float x, float q) {
    float d = x - q;
    return __expf(-16.f * d * d);
}

// One cooperative kernel: minmax -> grid.sync -> main write phase -> grid.sync
// -> finalize. Saves 2 launches + k_minmax's latency-bound standalone pass.
__global__ __launch_bounds__(256) void k_fused(const float* __restrict__ x,
                                               float* __restrict__ out,
                                               float* __restrict__ ws) {
    cg::grid_group grid = cg::this_grid();
    const int t = threadIdx.x;
    const int bid = blockIdx.x;
    __shared__ float smn[4], smx[4];
    __shared__ float red[4][8];

    // ---- phase 1: per-block min/max over an 8KB slice of x ----
    {
        const float4* x4 = (const float4*)x;
        float4 a = x4[bid * 512 + t];
        float4 b = x4[bid * 512 + 256 + t];
        float mn = fminf(fminf(fminf(a.x, a.y), fminf(a.z, a.w)),
                         fminf(fminf(b.x, b.y), fminf(b.z, b.w)));
        float mx = fmaxf(fmaxf(fmaxf(a.x, a.y), fmaxf(a.z, a.w)),
                         fmaxf(fmaxf(b.x, b.y), fmaxf(b.z, b.w)));
        #pragma unroll
        for (int m = 1; m < 64; m <<= 1) {
            mn = fminf(mn, __shfl_xor(mn, m, 64));
            mx = fmaxf(mx, __shfl_xor(mx, m, 64));
        }
        if ((t & 63) == 0) { smn[t >> 6] = mn; smx[t >> 6] = mx; }
        __syncthreads();
        if (t == 0) {
            ws[WS_MINP + bid] = fminf(fminf(smn[0], smn[1]), fminf(smn[2], smn[3]));
            ws[WS_MAXP + bid] = fmaxf(fmaxf(smx[0], smx[1]), fmaxf(smx[2], smx[3]));
        }
    }
    grid.sync();

    // ---- phase 2 prologue: every block reduces the 512 partials ----
    float mn = fminf(ws[WS_MINP + t], ws[WS_MINP + 256 + t]);
    float mx = fmaxf(ws[WS_MAXP + t], ws[WS_MAXP + 256 + t]);
    #pragma unroll
    for (int m = 1; m < 64; m <<= 1) {
        mn = fminf(mn, __shfl_xor(mn, m, 64));
        mx = fmaxf(mx, __shfl_xor(mx, m, 64));
    }
    if ((t & 63) == 0) { smn[t >> 6] = mn; smx[t >> 6] = mx; }
    __syncthreads();
    const float mnv = fminf(fminf(smn[0], smn[1]), fminf(smn[2], smn[3]));
    const float mxv = fmaxf(fmaxf(smx[0], smx[1]), fmaxf(smx[2], smx[3]));
    const float step = (mxv - mnv) * (1.0f / 7.0f);
    float qv[L];
    #pragma unroll
    for (int j = 0; j < L; ++j) qv[j] = qlev(mnv, step, mxv, j);

    float* __restrict__ quant = out + OUT0;
    float* __restrict__ co    = out + OUT0 + QUANT_ELEMS;

    // ---- phase 2: i-grouped plane-major write phase (identical to R7) ----
    // XCD swizzle: bid%8 = XCD; sbid gives each XCD 4 whole chunks of x.
    const int sbid = (bid & 7) * (NUNITS / 8) + (bid >> 3);
    const int c = sbid >> 4, i = (sbid >> 1) & 7, half = sbid & 1;
    const int r0 = c * 32 + half * UROWS;
    const float qi = qv[i];

    const int w0 = t * 4;
    const bool ok3 = (w0 + 4 < W);     // lane 255's 4th shifted col is the pad

    // software pipeline: cur = row h, (nxt,e) = row h+1 (right source)
    float4 cur = *(const float4*)(x + r0 * W + w0);
    float4 nxt = make_float4(0.f, 0.f, 0.f, 0.f);
    float e = 0.f;
    if (r0 + 1 < H) {
        nxt = *(const float4*)(x + (r0 + 1) * W + w0);
        if (ok3) e = x[(r0 + 1) * W + w0 + 4];
    }

    float acc[L] = {0.f, 0.f, 0.f, 0.f, 0.f, 0.f, 0.f, 0.f};

    for (int r = 0; r < UROWS; ++r) {
        const int h = r0 + r;
        // prefetch row h+2 (next iteration's right row)
        float4 nx2 = make_float4(0.f, 0.f, 0.f, 0.f);
        float e2 = 0.f;
        if (h + 2 < H) {
            nx2 = *(const float4*)(x + (h + 2) * W + w0);
            if (ok3) e2 = x[(h + 2) * W + w0 + 4];
        }

        // l-exps for level i — these ARE quant[i] row h
        float l0 = ex16(cur.x, qi), l1 = ex16(cur.y, qi),
              l2 = ex16(cur.z, qi), l3 = ex16(cur.w, qi);
        float* qp = quant + (i * QH + h) * QW + w0;
        *(float4*)qp = make_float4(l0, l1, l2, l3);
        if (t == 255) qp[4] = 0.0f;     // right pad col (w == 1024)

        float* cb = co + (i * L) * (H * W) + h * W + w0;
        if (h + 1 < H) {
            #pragma unroll
            for (int j = 0; j < L; ++j) {
                const float q = qv[j];
                float p0 = ex16(nxt.y, q);
                float p1 = ex16(nxt.z, q);
                float p2 = ex16(nxt.w, q);
                float p3 = ok3 ? ex16(e, q) : 0.f;
                float v0 = l0 * p0, v1 = l1 * p1, v2 = l2 * p2, v3 = l3 * p3;
                *(float4*)(cb + j * (H * W)) = make_float4(v0, v1, v2, v3);
                acc[j] += (v0 + v1) + (v2 + v3);
            }
        } else {  // h == 1023: shifted row is the zero pad -> co row is zero
            #pragma unroll
            for (int j = 0; j < L; ++j)
                *(float4*)(cb + j * (H * W)) = make_float4(0.f, 0.f, 0.f, 0.f);
        }

        cur = nxt; nxt = nx2; e = e2;
    }

    // bottom pad row of quant plane i (h == 1024), owned by (c==31, half==1)
    if (c == NUNITS / 16 - 1 && half == 1) {
        for (int w = t; w < QW; w += 256)
            quant[(i * QH + H) * QW + w] = 0.0f;
    }

    // per-j wave reduce -> LDS -> 8 exclusive sta slots
    #pragma unroll
    for (int j = 0; j < L; ++j) {
        float a = acc[j];
        #pragma unroll
        for (int m = 1; m < 64; m <<= 1) a += __shfl_xor(a, m, 64);
        if ((t & 63) == 0) red[t >> 6][j] = a;
    }
    __syncthreads();
    if (t < L) {
        float s = (red[0][t] + red[1][t]) + (red[2][t] + red[3][t]);
        ws[WS_STA + (c * 2 + half) * 64 + i * 8 + t] = s;
    }

    grid.sync();

    // ---- phase 3: block 0 finalizes out[0..191] ----
    if (bid == 0 && t < 64) {
        float s = 0.f;
        #pragma unroll 8
        for (int u = 0; u < 64; ++u) s += ws[WS_STA + u * 64 + t];
        float tot = s;
        #pragma unroll
        for (int m = 1; m < 64; m <<= 1) tot += __shfl_xor(tot, m, 64);

        out[t]       = qv[t & 7];    // q_h[i][j] = q_levels[j]
        out[64 + t]  = qv[t >> 3];   // q_w[i][j] = q_levels[i]
        out[128 + t] = s / tot;      // normalized sta
    }
}

extern "C" void kernel_launch(void* const* d_in, const int* in_sizes, int n_in,
                              void* d_out, int out_size, void* d_ws, size_t ws_size,
                              hipStream_t stream) {
    const float* x = (const float*)d_in[0];
    float* out = (float*)d_out;
    float* ws = (float*)d_ws;

    void* args[] = {(void*)&x, (void*)&out, (void*)&ws};
    hipLaunchCooperativeKernel((const void*)k_fused, dim3(NUNITS), dim3(256),
                               args, 0, stream);
}

// Round 9
// 65.835 us; speedup vs baseline: 2.5031x; 2.5031x over previous
//
#include <hip/hip_runtime.h>

#define H 1024
#define W 1024
#define L 8
#define QH 1025
#define QW 1025
#define OUT0 192
#define QUANT_ELEMS (L * QH * QW)

#define UROWS 8               // rows per unit
#define NCHUNK 64             // chunks of 16 rows
#define NUNITS 1024           // 64 chunks x 8 i-groups x 2 halves = 4 blocks/CU
// unit u: c = u>>4, i = (u>>1)&7, half = u&1

// ws float slots (every slot written unconditionally every call -> no init
// kernel, no atomics, deterministic under graph replay):
// [0..255] min partials, [256..511] max partials,
// [512..8703] sta partials: slot (c*2+half)*64 + (i*8+j), exclusive per block
#define WS_MINP 0
#define WS_MAXP 256
#define WS_STA  512
#define NGROUP  (NCHUNK * 2)  // 128 sta groups

__device__ __forceinline__ float qlev(float mn, float step, float mx, int i) {
    return (i == L - 1) ? mx : mn + step * (float)i;
}
__device__ __forceinline__ float ex16(float x, float q) {
    float d = x - q;
    return __expf(-16.f * d * d);
}

__global__ __launch_bounds__(256) void k_minmax(const float4* __restrict__ x4,
                                                float* __restrict__ ws) {
    const int t = threadIdx.x, b = blockIdx.x;
    float mn = 1e30f, mx = -1e30f;
    #pragma unroll
    for (int i = 0; i < 4; ++i) {
        float4 v = x4[b * 1024 + i * 256 + t];
        mn = fminf(mn, fminf(fminf(v.x, v.y), fminf(v.z, v.w)));
        mx = fmaxf(mx, fmaxf(fmaxf(v.x, v.y), fmaxf(v.z, v.w)));
    }
    #pragma unroll
    for (int m = 1; m < 64; m <<= 1) {
        mn = fminf(mn, __shfl_xor(mn, m, 64));
        mx = fmaxf(mx, __shfl_xor(mx, m, 64));
    }
    __shared__ float smn[4], smx[4];
    if ((t & 63) == 0) { smn[t >> 6] = mn; smx[t >> 6] = mx; }
    __syncthreads();
    if (t == 0) {
        ws[WS_MINP + b] = fminf(fminf(smn[0], smn[1]), fminf(smn[2], smn[3]));
        ws[WS_MAXP + b] = fmaxf(fmaxf(smx[0], smx[1]), fmaxf(smx[2], smx[3]));
    }
}

// i-grouped plane-major (R7 body), 1024 blocks = 4/CU (16 waves/CU) to deepen
// the per-CU store queue. Unit (c,i,half): l-exps once for level i = quant
// plane i rows, p-exps once for all 8 j, writes 8 co planes + quant plane for
// its 8 rows. XCD swizzle: bid%8 = XCD; sbid gives each XCD 8 whole chunks.
__global__ __launch_bounds__(256) void k_main(const float* __restrict__ x,
                                              float* __restrict__ out,
                                              float* __restrict__ ws) {
    const int t = threadIdx.x;
    __shared__ float smn[4], smx[4];
    __shared__ float red[4][8];

    // prologue: reduce the 256 min/max partials (L2-resident)
    float mn = ws[WS_MINP + t], mx = ws[WS_MAXP + t];
    #pragma unroll
    for (int m = 1; m < 64; m <<= 1) {
        mn = fminf(mn, __shfl_xor(mn, m, 64));
        mx = fmaxf(mx, __shfl_xor(mx, m, 64));
    }
    if ((t & 63) == 0) { smn[t >> 6] = mn; smx[t >> 6] = mx; }
    __syncthreads();
    const float mnv = fminf(fminf(smn[0], smn[1]), fminf(smn[2], smn[3]));
    const float mxv = fmaxf(fmaxf(smx[0], smx[1]), fmaxf(smx[2], smx[3]));
    const float step = (mxv - mnv) * (1.0f / 7.0f);
    float qv[L];
    #pragma unroll
    for (int j = 0; j < L; ++j) qv[j] = qlev(mnv, step, mxv, j);

    float* __restrict__ quant = out + OUT0;
    float* __restrict__ co    = out + OUT0 + QUANT_ELEMS;

    const int sbid = (blockIdx.x & 7) * (NUNITS / 8) + (blockIdx.x >> 3);
    const int c = sbid >> 4, i = (sbid >> 1) & 7, half = sbid & 1;
    const int r0 = c * 16 + half * UROWS;
    const float qi = qv[i];

    const int w0 = t * 4;
    const bool ok3 = (w0 + 4 < W);     // lane 255's 4th shifted col is the pad

    // software pipeline: cur = row h, (nxt,e) = row h+1 (right source)
    float4 cur = *(const float4*)(x + r0 * W + w0);
    float4 nxt = make_float4(0.f, 0.f, 0.f, 0.f);
    float e = 0.f;
    if (r0 + 1 < H) {
        nxt = *(const float4*)(x + (r0 + 1) * W + w0);
        if (ok3) e = x[(r0 + 1) * W + w0 + 4];
    }

    float acc[L] = {0.f, 0.f, 0.f, 0.f, 0.f, 0.f, 0.f, 0.f};

    for (int r = 0; r < UROWS; ++r) {
        const int h = r0 + r;
        // prefetch row h+2 (next iteration's right row)
        float4 nx2 = make_float4(0.f, 0.f, 0.f, 0.f);
        float e2 = 0.f;
        if (h + 2 < H) {
            nx2 = *(const float4*)(x + (h + 2) * W + w0);
            if (ok3) e2 = x[(h + 2) * W + w0 + 4];
        }

        // l-exps for level i — these ARE quant[i] row h
        float l0 = ex16(cur.x, qi), l1 = ex16(cur.y, qi),
              l2 = ex16(cur.z, qi), l3 = ex16(cur.w, qi);
        float* qp = quant + (i * QH + h) * QW + w0;
        *(float4*)qp = make_float4(l0, l1, l2, l3);
        if (t == 255) qp[4] = 0.0f;     // right pad col (w == 1024)

        float* cb = co + (i * L) * (H * W) + h * W + w0;
        if (h + 1 < H) {
            #pragma unroll
            for (int j = 0; j < L; ++j) {
                const float q = qv[j];
                float p0 = ex16(nxt.y, q);
                float p1 = ex16(nxt.z, q);
                float p2 = ex16(nxt.w, q);
                float p3 = ok3 ? ex16(e, q) : 0.f;
                float v0 = l0 * p0, v1 = l1 * p1, v2 = l2 * p2, v3 = l3 * p3;
                *(float4*)(cb + j * (H * W)) = make_float4(v0, v1, v2, v3);
                acc[j] += (v0 + v1) + (v2 + v3);
            }
        } else {  // h == 1023: shifted row is the zero pad -> co row is zero
            #pragma unroll
            for (int j = 0; j < L; ++j)
                *(float4*)(cb + j * (H * W)) = make_float4(0.f, 0.f, 0.f, 0.f);
        }

        cur = nxt; nxt = nx2; e = e2;
    }

    // bottom pad row of quant plane i (h == 1024), owned by (c==63, half==1)
    if (c == NCHUNK - 1 && half == 1) {
        for (int w = t; w < QW; w += 256)
            quant[(i * QH + H) * QW + w] = 0.0f;
    }

    // per-j wave reduce -> LDS -> 8 exclusive sta slots
    #pragma unroll
    for (int j = 0; j < L; ++j) {
        float a = acc[j];
        #pragma unroll
        for (int m = 1; m < 64; m <<= 1) a += __shfl_xor(a, m, 64);
        if ((t & 63) == 0) red[t >> 6][j] = a;
    }
    __syncthreads();
    if (t < L) {
        float s = (red[0][t] + red[1][t]) + (red[2][t] + red[3][t]);
        ws[WS_STA + (c * 2 + half) * 64 + i * 8 + t] = s;
    }
}

__global__ void k_final(float* __restrict__ out, const float* __restrict__ ws) {
    const int t = threadIdx.x;  // 64 threads
    float mn = 1e30f, mx = -1e30f;
    #pragma unroll
    for (int i = 0; i < 4; ++i) {
        mn = fminf(mn, ws[WS_MINP + i * 64 + t]);
        mx = fmaxf(mx, ws[WS_MAXP + i * 64 + t]);
    }
    #pragma unroll
    for (int m = 1; m < 64; m <<= 1) {
        mn = fminf(mn, __shfl_xor(mn, m, 64));
        mx = fmaxf(mx, __shfl_xor(mx, m, 64));
    }
    const float step = (mx - mn) * (1.0f / 7.0f);

    float s = 0.f;
    #pragma unroll 8
    for (int u = 0; u < NGROUP; ++u) s += ws[WS_STA + u * 64 + t];
    float tot = s;
    #pragma unroll
    for (int m = 1; m < 64; m <<= 1) tot += __shfl_xor(tot, m, 64);

    out[t]       = qlev(mn, step, mx, t & 7);   // q_h[i][j] = q_levels[j]
    out[64 + t]  = qlev(mn, step, mx, t >> 3);  // q_w[i][j] = q_levels[i]
    out[128 + t] = s / tot;                     // normalized sta
}

extern "C" void kernel_launch(void* const* d_in, const int* in_sizes, int n_in,
                              void* d_out, int out_size, void* d_ws, size_t ws_size,
                              hipStream_t stream) {
    const float* x = (const float*)d_in[0];
    float* out = (float*)d_out;
    float* ws = (float*)d_ws;

    k_minmax<<<dim3(256), dim3(256), 0, stream>>>((const float4*)x, ws);
    k_main<<<dim3(NUNITS), dim3(256), 0, stream>>>(x, out, ws);
    k_final<<<dim3(1), dim3(64), 0, stream>>>(out, ws);
}

// Round 10
// 62.669 us; speedup vs baseline: 2.6296x; 1.0505x over previous
//
#include <hip/hip_runtime.h>

#define H 1024
#define W 1024
#define L 8
#define QH 1025
#define QW 1025
#define OUT0 192
#define QUANT_ELEMS (L * QH * QW)

#define UROWS 16              // rows per unit (R7 config — best measured)
#define NCHUNK 32             // chunks of 32 rows
#define NUNITS 512            // 32 chunks x 8 i-groups x 2 halves = 2 blocks/CU
#define NGROUP 64             // sta groups = chunks*halves

// ws float slots (every slot written unconditionally every call -> no init
// kernel, no atomics, deterministic under graph replay):
// [0..1023] min partials, [1024..2047] max partials,
// [2048..6143] sta partials: slot (c*2+half)*64 + (i*8+j), exclusive per block
#define WS_MINP 0
#define WS_MAXP 1024
#define WS_STA  2048

__device__ __forceinline__ float qlev(float mn, float step, float mx, int i) {
    return (i == L - 1) ? mx : mn + step * (float)i;
}
__device__ __forceinline__ float ex16(float x, float q) {
    float d = x - q;
    return __expf(-16.f * d * d);
}

// 1024 blocks x 1 float4/thread: ONE parallel HBM round-trip (was 4 dependent).
__global__ __launch_bounds__(256) void k_minmax(const float4* __restrict__ x4,
                                                float* __restrict__ ws) {
    const int t = threadIdx.x, b = blockIdx.x;
    float4 v = x4[b * 256 + t];
    float mn = fminf(fminf(v.x, v.y), fminf(v.z, v.w));
    float mx = fmaxf(fmaxf(v.x, v.y), fmaxf(v.z, v.w));
    #pragma unroll
    for (int m = 1; m < 64; m <<= 1) {
        mn = fminf(mn, __shfl_xor(mn, m, 64));
        mx = fmaxf(mx, __shfl_xor(mx, m, 64));
    }
    __shared__ float smn[4], smx[4];
    if ((t & 63) == 0) { smn[t >> 6] = mn; smx[t >> 6] = mx; }
    __syncthreads();
    if (t == 0) {
        ws[WS_MINP + b] = fminf(fminf(smn[0], smn[1]), fminf(smn[2], smn[3]));
        ws[WS_MAXP + b] = fmaxf(fmaxf(smx[0], smx[1]), fmaxf(smx[2], smx[3]));
    }
}

// R7 k_main, byte-identical write phase (best measured: 64.7 us total).
// i-grouped plane-major: unit (c,i,half) computes l-exps once for level i
// (= quant plane i rows), p-exps once for all 8 j, writes 8 co planes +
// quant plane for its 16 rows. XCD swizzle: bid%8 = XCD; sbid gives each
// XCD 4 whole chunks of x (single-L2 fetch, measured FETCH 4.4 MB).
__global__ __launch_bounds__(256) void k_main(const float* __restrict__ x,
                                              float* __restrict__ out,
                                              float* __restrict__ ws) {
    const int t = threadIdx.x;
    __shared__ float smn[4], smx[4];
    __shared__ float red[4][8];

    // prologue: reduce the 1024 min/max partials (L2-resident, 4 indep loads)
    float mn = fminf(fminf(ws[WS_MINP + t], ws[WS_MINP + 256 + t]),
                     fminf(ws[WS_MINP + 512 + t], ws[WS_MINP + 768 + t]));
    float mx = fmaxf(fmaxf(ws[WS_MAXP + t], ws[WS_MAXP + 256 + t]),
                     fmaxf(ws[WS_MAXP + 512 + t], ws[WS_MAXP + 768 + t]));
    #pragma unroll
    for (int m = 1; m < 64; m <<= 1) {
        mn = fminf(mn, __shfl_xor(mn, m, 64));
        mx = fmaxf(mx, __shfl_xor(mx, m, 64));
    }
    if ((t & 63) == 0) { smn[t >> 6] = mn; smx[t >> 6] = mx; }
    __syncthreads();
    const float mnv = fminf(fminf(smn[0], smn[1]), fminf(smn[2], smn[3]));
    const float mxv = fmaxf(fmaxf(smx[0], smx[1]), fmaxf(smx[2], smx[3]));
    const float step = (mxv - mnv) * (1.0f / 7.0f);
    float qv[L];
    #pragma unroll
    for (int j = 0; j < L; ++j) qv[j] = qlev(mnv, step, mxv, j);

    float* __restrict__ quant = out + OUT0;
    float* __restrict__ co    = out + OUT0 + QUANT_ELEMS;

    const int sbid = (blockIdx.x & 7) * (NUNITS / 8) + (blockIdx.x >> 3);
    const int c = sbid >> 4, i = (sbid >> 1) & 7, half = sbid & 1;
    const int r0 = c * 32 + half * UROWS;
    const float qi = qv[i];

    const int w0 = t * 4;
    const bool ok3 = (w0 + 4 < W);     // lane 255's 4th shifted col is the pad

    // software pipeline: cur = row h, (nxt,e) = row h+1 (right source)
    float4 cur = *(const float4*)(x + r0 * W + w0);
    float4 nxt = make_float4(0.f, 0.f, 0.f, 0.f);
    float e = 0.f;
    if (r0 + 1 < H) {
        nxt = *(const float4*)(x + (r0 + 1) * W + w0);
        if (ok3) e = x[(r0 + 1) * W + w0 + 4];
    }

    float acc[L] = {0.f, 0.f, 0.f, 0.f, 0.f, 0.f, 0.f, 0.f};

    for (int r = 0; r < UROWS; ++r) {
        const int h = r0 + r;
        // prefetch row h+2 (next iteration's right row)
        float4 nx2 = make_float4(0.f, 0.f, 0.f, 0.f);
        float e2 = 0.f;
        if (h + 2 < H) {
            nx2 = *(const float4*)(x + (h + 2) * W + w0);
            if (ok3) e2 = x[(h + 2) * W + w0 + 4];
        }

        // l-exps for level i — these ARE quant[i] row h
        float l0 = ex16(cur.x, qi), l1 = ex16(cur.y, qi),
              l2 = ex16(cur.z, qi), l3 = ex16(cur.w, qi);
        float* qp = quant + (i * QH + h) * QW + w0;
        *(float4*)qp = make_float4(l0, l1, l2, l3);
        if (t == 255) qp[4] = 0.0f;     // right pad col (w == 1024)

        float* cb = co + (i * L) * (H * W) + h * W + w0;
        if (h + 1 < H) {
            #pragma unroll
            for (int j = 0; j < L; ++j) {
                const float q = qv[j];
                float p0 = ex16(nxt.y, q);
                float p1 = ex16(nxt.z, q);
                float p2 = ex16(nxt.w, q);
                float p3 = ok3 ? ex16(e, q) : 0.f;
                float v0 = l0 * p0, v1 = l1 * p1, v2 = l2 * p2, v3 = l3 * p3;
                *(float4*)(cb + j * (H * W)) = make_float4(v0, v1, v2, v3);
                acc[j] += (v0 + v1) + (v2 + v3);
            }
        } else {  // h == 1023: shifted row is the zero pad -> co row is zero
            #pragma unroll
            for (int j = 0; j < L; ++j)
                *(float4*)(cb + j * (H * W)) = make_float4(0.f, 0.f, 0.f, 0.f);
        }

        cur = nxt; nxt = nx2; e = e2;
    }

    // bottom pad row of quant plane i (h == 1024), owned by (c==31, half==1)
    if (c == NCHUNK - 1 && half == 1) {
        for (int w = t; w < QW; w += 256)
            quant[(i * QH + H) * QW + w] = 0.0f;
    }

    // per-j wave reduce -> LDS -> 8 exclusive sta slots
    #pragma unroll
    for (int j = 0; j < L; ++j) {
        float a = acc[j];
        #pragma unroll
        for (int m = 1; m < 64; m <<= 1) a += __shfl_xor(a, m, 64);
        if ((t & 63) == 0) red[t >> 6][j] = a;
    }
    __syncthreads();
    if (t < L) {
        float s = (red[0][t] + red[1][t]) + (red[2][t] + red[3][t]);
        ws[WS_STA + (c * 2 + half) * 64 + i * 8 + t] = s;
    }
}

// 4 waves x 16 groups each (was 1 wave x 64): 4x shorter serial load chain.
__global__ __launch_bounds__(256) void k_final(float* __restrict__ out,
                                               const float* __restrict__ ws) {
    const int t = threadIdx.x, wv = t >> 6, ln = t & 63;
    __shared__ float red[4][64];

    float s = 0.f;
    #pragma unroll
    for (int g = 0; g < NGROUP / 4; ++g)
        s += ws[WS_STA + (wv * (NGROUP / 4) + g) * 64 + ln];
    red[wv][ln] = s;

    float mn = fminf(fminf(ws[WS_MINP + t], ws[WS_MINP + 256 + t]),
                     fminf(ws[WS_MINP + 512 + t], ws[WS_MINP + 768 + t]));
    float mx = fmaxf(fmaxf(ws[WS_MAXP + t], ws[WS_MAXP + 256 + t]),
                     fmaxf(ws[WS_MAXP + 512 + t], ws[WS_MAXP + 768 + t]));
    #pragma unroll
    for (int m = 1; m < 64; m <<= 1) {
        mn = fminf(mn, __shfl_xor(mn, m, 64));
        mx = fmaxf(mx, __shfl_xor(mx, m, 64));
    }
    __shared__ float smn[4], smx[4];
    if (ln == 0) { smn[wv] = mn; smx[wv] = mx; }
    __syncthreads();

    if (t < 64) {
        const float mnv = fminf(fminf(smn[0], smn[1]), fminf(smn[2], smn[3]));
        const float mxv = fmaxf(fmaxf(smx[0], smx[1]), fmaxf(smx[2], smx[3]));
        const float step = (mxv - mnv) * (1.0f / 7.0f);

        float sc = (red[0][t] + red[1][t]) + (red[2][t] + red[3][t]);
        float tot = sc;
        #pragma unroll
        for (int m = 1; m < 64; m <<= 1) tot += __shfl_xor(tot, m, 64);

        out[t]       = qlev(mnv, step, mxv, t & 7);   // q_h[i][j] = q_levels[j]
        out[64 + t]  = qlev(mnv, step, mxv, t >> 3);  // q_w[i][j] = q_levels[i]
        out[128 + t] = sc / tot;                      // normalized sta
    }
}

extern "C" void kernel_launch(void* const* d_in, const int* in_sizes, int n_in,
                              void* d_out, int out_size, void* d_ws, size_t ws_size,
                              hipStream_t stream) {
    const float* x = (const float*)d_in[0];
    float* out = (float*)d_out;
    float* ws = (float*)d_ws;

    k_minmax<<<dim3(1024), dim3(256), 0, stream>>>((const float4*)x, ws);
    k_main<<<dim3(NUNITS), dim3(256), 0, stream>>>(x, out, ws);
    k_final<<<dim3(1), dim3(256), 0, stream>>>(out, ws);
}